// Round 6
// baseline (1372.352 us; speedup 1.0000x reference)
//
#include <hip/hip_runtime.h>

#define N_NODES 100000
#define N_EDGES 1600000
#define D 128
#define NB 196              // buckets of 512 nodes: 196*512 = 100352 >= N_NODES
#define EPT 10              // edges per thread in binning
#define CHUNK 2560          // 256 threads * EPT
#define BIN_BLOCKS 625      // 625 * 2560 = 1,600,000 exactly
#define CVT_X_BLOCKS 6250   // 6250*256*8 = 12.8M elements

typedef __bf16 bf16x8 __attribute__((ext_vector_type(8)));
typedef float f32x4 __attribute__((ext_vector_type(4)));

__device__ __forceinline__ unsigned f2bf(float f) {
    unsigned u = __float_as_uint(f);
    return (u + 0x7fffu + ((u >> 16) & 1u)) >> 16;   // RNE
}
__device__ __forceinline__ float bf_lo(unsigned u) { return __uint_as_float(u << 16); }
__device__ __forceinline__ float bf_hi(unsigned u) { return __uint_as_float(u & 0xffff0000u); }

// sliced layout: elem(n,c) at ((c>>4)*N + n)*16 + (c&15)  -- 8 slices of 16 ch

// ---------------- convert x -> bf16 sliced  +  build Wt ----------------
__global__ __launch_bounds__(256) void cvt_kernel(const float* __restrict__ x,
                                                  const float* __restrict__ Wrel,
                                                  const float* __restrict__ Wroot,
                                                  unsigned short* __restrict__ x_sl,
                                                  unsigned short* __restrict__ Wt) {
    int b = blockIdx.x;
    if (b < CVT_X_BLOCKS) {
        int idx = b * 256 + threadIdx.x;   // 8-channel group id
        int n = idx >> 4;
        int c0 = (idx & 15) * 8;
        float4 v0 = *(const float4*)(x + (size_t)n * D + c0);
        float4 v1 = *(const float4*)(x + (size_t)n * D + c0 + 4);
        uint4 p;
        p.x = f2bf(v0.x) | (f2bf(v0.y) << 16);
        p.y = f2bf(v0.z) | (f2bf(v0.w) << 16);
        p.z = f2bf(v1.x) | (f2bf(v1.y) << 16);
        p.w = f2bf(v1.z) | (f2bf(v1.w) << 16);
        *(uint4*)(x_sl + ((size_t)(c0 >> 4) * N_NODES + n) * 16 + (c0 & 15)) = p;
    } else {
        int c = b - CVT_X_BLOCKS;          // 0..127
        int k = threadIdx.x;               // 0..255
        float v = (k < 128) ? Wrel[k * D + c] : Wroot[(k - 128) * D + c];
        Wt[c * 256 + k] = (unsigned short)f2bf(v);
    }
}

// ---------------- bucket histogram ----------------
__global__ __launch_bounds__(256) void bhist_kernel(const int* __restrict__ ei,
                                                    int* __restrict__ bcount) {
    __shared__ int h[256];
    int t = threadIdx.x;
    h[t] = 0;
    __syncthreads();
    int base = blockIdx.x * CHUNK;
#pragma unroll
    for (int i = 0; i < EPT; ++i) {
        int dst = ei[N_EDGES + base + i * 256 + t];
        atomicAdd(&h[dst >> 9], 1);
    }
    __syncthreads();
    if (t < NB && h[t]) atomicAdd(&bcount[t], h[t]);
}

// ---------------- bucket scan (1 block) ----------------
__global__ __launch_bounds__(256) void bscan_kernel(const int* __restrict__ bcount,
                                                    int* __restrict__ bucket_base,
                                                    int* __restrict__ bcur) {
    __shared__ int s[256];
    int t = threadIdx.x;
    int v = (t < NB) ? bcount[t] : 0;
    s[t] = v;
    __syncthreads();
    for (int off = 1; off < 256; off <<= 1) {
        int a = (t >= off) ? s[t - off] : 0;
        __syncthreads();
        s[t] += a;
        __syncthreads();
    }
    int excl = s[t] - v;
    if (t < NB) {
        bucket_base[t] = excl;
        bcur[t] = excl;
    }
    if (t == NB) bucket_base[NB] = N_EDGES;
}

// ---------------- binify: block-local multisplit -> packed edge codes ----------------
// code: src in bits 0..16, local dst (dst&511) in bits 17..25
__global__ __launch_bounds__(256) void binify_kernel(const int* __restrict__ ei,
                                                     int* __restrict__ bcur,
                                                     unsigned* __restrict__ epk) {
    __shared__ int lhist[256];
    __shared__ int lstart[256];
    __shared__ int lfill[256];
    __shared__ int gbase[256];
    __shared__ uint2 stage[CHUNK];

    int t = threadIdx.x;
    int base = blockIdx.x * CHUNK;
    lhist[t] = 0;
    lfill[t] = 0;
    __syncthreads();

    int src[EPT], dst[EPT];
#pragma unroll
    for (int i = 0; i < EPT; ++i) {
        int e = base + i * 256 + t;
        src[i] = ei[e];
        dst[i] = ei[N_EDGES + e];
        atomicAdd(&lhist[dst[i] >> 9], 1);
    }
    __syncthreads();

    int v = lhist[t];
    lstart[t] = v;
    __syncthreads();
    for (int off = 1; off < 256; off <<= 1) {
        int a = (t >= off) ? lstart[t - off] : 0;
        __syncthreads();
        lstart[t] += a;
        __syncthreads();
    }
    int excl = lstart[t] - v;
    if (t < NB && v > 0) gbase[t] = atomicAdd(&bcur[t], v);
    __syncthreads();
    lstart[t] = excl;
    __syncthreads();

#pragma unroll
    for (int i = 0; i < EPT; ++i) {
        int b = dst[i] >> 9;
        int lp = atomicAdd(&lfill[b], 1);
        stage[lstart[b] + lp] = make_uint2((unsigned)src[i], (unsigned)dst[i]);
    }
    __syncthreads();

    for (int i = t; i < CHUNK; i += 256) {
        uint2 p = stage[i];
        int b = (int)(p.y >> 9);
        unsigned code = p.x | ((p.y & 511u) << 17);
        __builtin_nontemporal_store(code, &epk[gbase[b] + (i - lstart[b])]);
    }
}

// ---------------- gather: edge-parallel, LDS accumulate, XCD-sliced ----------------
// block = (bucket = blockIdx>>3 [512 dst nodes], slice = blockIdx&7 [16 ch])
#define FSTRIDE 17
__global__ __launch_bounds__(256) void gather_lds(const unsigned short* __restrict__ x_sl,
                                                  const int* __restrict__ bucket_base,
                                                  const unsigned* __restrict__ epk,
                                                  unsigned short* __restrict__ aggr_sl) {
    __shared__ float facc[512 * FSTRIDE];   // 34 KB
    int t = threadIdx.x;
    int s = blockIdx.x & 7;
    int b = blockIdx.x >> 3;

    for (int j = t; j < 512 * FSTRIDE; j += 256) facc[j] = 0.f;
    __syncthreads();

    int pbeg = bucket_base[b];
    int pend = bucket_base[b + 1];
    const unsigned short* xs = x_sl + (size_t)s * N_NODES * 16;

    for (int i = pbeg + t; i < pend; i += 256) {
        unsigned code = __builtin_nontemporal_load(&epk[i]);
        int src = (int)(code & 0x1FFFFu);
        int ld = (int)(code >> 17);
        const uint4* row = (const uint4*)(xs + (size_t)src * 16);
        uint4 lo = row[0];
        uint4 hi = row[1];
        float* f = &facc[ld * FSTRIDE];
        __hip_atomic_fetch_add(&f[0],  bf_lo(lo.x), __ATOMIC_RELAXED, __HIP_MEMORY_SCOPE_WORKGROUP);
        __hip_atomic_fetch_add(&f[1],  bf_hi(lo.x), __ATOMIC_RELAXED, __HIP_MEMORY_SCOPE_WORKGROUP);
        __hip_atomic_fetch_add(&f[2],  bf_lo(lo.y), __ATOMIC_RELAXED, __HIP_MEMORY_SCOPE_WORKGROUP);
        __hip_atomic_fetch_add(&f[3],  bf_hi(lo.y), __ATOMIC_RELAXED, __HIP_MEMORY_SCOPE_WORKGROUP);
        __hip_atomic_fetch_add(&f[4],  bf_lo(lo.z), __ATOMIC_RELAXED, __HIP_MEMORY_SCOPE_WORKGROUP);
        __hip_atomic_fetch_add(&f[5],  bf_hi(lo.z), __ATOMIC_RELAXED, __HIP_MEMORY_SCOPE_WORKGROUP);
        __hip_atomic_fetch_add(&f[6],  bf_lo(lo.w), __ATOMIC_RELAXED, __HIP_MEMORY_SCOPE_WORKGROUP);
        __hip_atomic_fetch_add(&f[7],  bf_hi(lo.w), __ATOMIC_RELAXED, __HIP_MEMORY_SCOPE_WORKGROUP);
        __hip_atomic_fetch_add(&f[8],  bf_lo(hi.x), __ATOMIC_RELAXED, __HIP_MEMORY_SCOPE_WORKGROUP);
        __hip_atomic_fetch_add(&f[9],  bf_hi(hi.x), __ATOMIC_RELAXED, __HIP_MEMORY_SCOPE_WORKGROUP);
        __hip_atomic_fetch_add(&f[10], bf_lo(hi.y), __ATOMIC_RELAXED, __HIP_MEMORY_SCOPE_WORKGROUP);
        __hip_atomic_fetch_add(&f[11], bf_hi(hi.y), __ATOMIC_RELAXED, __HIP_MEMORY_SCOPE_WORKGROUP);
        __hip_atomic_fetch_add(&f[12], bf_lo(hi.z), __ATOMIC_RELAXED, __HIP_MEMORY_SCOPE_WORKGROUP);
        __hip_atomic_fetch_add(&f[13], bf_hi(hi.z), __ATOMIC_RELAXED, __HIP_MEMORY_SCOPE_WORKGROUP);
        __hip_atomic_fetch_add(&f[14], bf_lo(hi.w), __ATOMIC_RELAXED, __HIP_MEMORY_SCOPE_WORKGROUP);
        __hip_atomic_fetch_add(&f[15], bf_hi(hi.w), __ATOMIC_RELAXED, __HIP_MEMORY_SCOPE_WORKGROUP);
    }
    __syncthreads();

    // write out: 512 nodes x 16 ch bf16 (32 B per node), 2 nodes per thread
#pragma unroll
    for (int rep = 0; rep < 2; ++rep) {
        int n = rep * 256 + t;
        int gnode = (b << 9) + n;
        if (gnode < N_NODES) {
            const float* f = &facc[n * FSTRIDE];
            uint4 o0;
            o0.x = f2bf(f[0]) | (f2bf(f[1]) << 16);
            o0.y = f2bf(f[2]) | (f2bf(f[3]) << 16);
            o0.z = f2bf(f[4]) | (f2bf(f[5]) << 16);
            o0.w = f2bf(f[6]) | (f2bf(f[7]) << 16);
            uint4 o1;
            o1.x = f2bf(f[8])  | (f2bf(f[9])  << 16);
            o1.y = f2bf(f[10]) | (f2bf(f[11]) << 16);
            o1.z = f2bf(f[12]) | (f2bf(f[13]) << 16);
            o1.w = f2bf(f[14]) | (f2bf(f[15]) << 16);
            uint4* dst = (uint4*)(aggr_sl + ((size_t)s * N_NODES + gnode) * 16);
            dst[0] = o0;
            dst[1] = o1;
        }
    }
}

// ---------------- MFMA GEMM + fused BN stats ----------------
#define LDSTRIDE 40
__global__ __launch_bounds__(256) void gemm_mfma(const unsigned short* __restrict__ aggr_sl,
                                                 const unsigned short* __restrict__ x_sl,
                                                 const unsigned short* __restrict__ Wt,
                                                 const float* __restrict__ brel,
                                                 float* __restrict__ out,
                                                 float* __restrict__ gsum,
                                                 float* __restrict__ gss) {
    __shared__ unsigned short As[128][LDSTRIDE];
    __shared__ unsigned short Bs[128][LDSTRIDE];
    __shared__ float sbias[128];
    __shared__ float SredS[4][128];
    __shared__ float SredQ[4][128];

    const int t = threadIdx.x;
    const int wave = t >> 6;
    const int lane = t & 63;
    const int quad = lane >> 4;
    const int l16 = lane & 15;
    const int blockRow = blockIdx.x * 128;

    if (t < 128) sbias[t] = brel[t];

    f32x4 acc[2][8];
#pragma unroll
    for (int i = 0; i < 2; ++i)
#pragma unroll
        for (int j = 0; j < 8; ++j) acc[i][j] = (f32x4){0.f, 0.f, 0.f, 0.f};

    for (int kc = 0; kc < 8; ++kc) {
        const unsigned short* Asrc = (kc < 4) ? aggr_sl : x_sl;
        const int k0 = (kc & 3) * 32;
#pragma unroll
        for (int s = t; s < 512; s += 256) {
            int row = s >> 2;
            int q = (s & 3) * 8;
            int c = k0 + q;
            int grow = blockRow + row;
            uint4 v = make_uint4(0, 0, 0, 0);
            if (grow < N_NODES)
                v = *(const uint4*)(Asrc + ((size_t)(c >> 4) * N_NODES + grow) * 16 + (c & 15));
            *(uint4*)&As[row][q] = v;
        }
#pragma unroll
        for (int s = t; s < 512; s += 256) {
            int col = s >> 2;
            int q = (s & 3) * 8;
            uint4 v = *(const uint4*)(Wt + col * 256 + kc * 32 + q);
            *(uint4*)&Bs[col][q] = v;
        }
        __syncthreads();

        bf16x8 afrag0 = *(bf16x8*)&As[wave * 32 + l16][quad * 8];
        bf16x8 afrag1 = *(bf16x8*)&As[wave * 32 + 16 + l16][quad * 8];
#pragma unroll
        for (int ct = 0; ct < 8; ++ct) {
            bf16x8 bfrag = *(bf16x8*)&Bs[ct * 16 + l16][quad * 8];
            acc[0][ct] = __builtin_amdgcn_mfma_f32_16x16x32_bf16(afrag0, bfrag, acc[0][ct], 0, 0, 0);
            acc[1][ct] = __builtin_amdgcn_mfma_f32_16x16x32_bf16(afrag1, bfrag, acc[1][ct], 0, 0, 0);
        }
        __syncthreads();
    }

    float csum[8], css[8];
#pragma unroll
    for (int ct = 0; ct < 8; ++ct) { csum[ct] = 0.f; css[ct] = 0.f; }

#pragma unroll
    for (int rt = 0; rt < 2; ++rt) {
#pragma unroll
        for (int ct = 0; ct < 8; ++ct) {
            int col = ct * 16 + l16;
            float bv = sbias[col];
#pragma unroll
            for (int reg = 0; reg < 4; ++reg) {
                int row = blockRow + wave * 32 + rt * 16 + quad * 4 + reg;
                if (row < N_NODES) {
                    float v = acc[rt][ct][reg] + bv;
                    out[(size_t)row * D + col] = v;
                    csum[ct] += v;
                    css[ct] += v * v;
                }
            }
        }
    }
#pragma unroll
    for (int ct = 0; ct < 8; ++ct) {
        float s = csum[ct], q = css[ct];
        s += __shfl_xor(s, 16);
        s += __shfl_xor(s, 32);
        q += __shfl_xor(q, 16);
        q += __shfl_xor(q, 32);
        if (quad == 0) {
            SredS[wave][ct * 16 + l16] = s;
            SredQ[wave][ct * 16 + l16] = q;
        }
    }
    __syncthreads();
    if (t < 128) {
        float s = SredS[0][t] + SredS[1][t] + SredS[2][t] + SredS[3][t];
        float q = SredQ[0][t] + SredQ[1][t] + SredQ[2][t] + SredQ[3][t];
        unsafeAtomicAdd(&gsum[t], s);
        unsafeAtomicAdd(&gss[t], q);
    }
}

// ---------------- normalize + relu ----------------
__global__ __launch_bounds__(256) void norm_kernel(float* __restrict__ h,
                                                   const float* __restrict__ gsum,
                                                   const float* __restrict__ gss,
                                                   const float* __restrict__ gamma,
                                                   const float* __restrict__ beta) {
    __shared__ float sscale[128];
    __shared__ float sshift[128];
    int t = threadIdx.x;
    if (t < 128) {
        const float inv_n = 1.0f / (float)N_NODES;
        float mean = gsum[t] * inv_n;
        float var = gss[t] * inv_n - mean * mean;
        float rs = rsqrtf(var + 1e-5f);
        float sc = gamma[t] * rs;
        sscale[t] = sc;
        sshift[t] = beta[t] - mean * sc;
    }
    __syncthreads();
    size_t e = ((size_t)blockIdx.x * 256 + t) * 4;
    if (e >= (size_t)N_NODES * D) return;
    int c = (int)(e & 127);
    float4 v = *(float4*)(h + e);
    v.x = fmaxf(v.x * sscale[c + 0] + sshift[c + 0], 0.f);
    v.y = fmaxf(v.y * sscale[c + 1] + sshift[c + 1], 0.f);
    v.z = fmaxf(v.z * sscale[c + 2] + sshift[c + 2], 0.f);
    v.w = fmaxf(v.w * sscale[c + 3] + sshift[c + 3], 0.f);
    *(float4*)(h + e) = v;
}

extern "C" void kernel_launch(void* const* d_in, const int* in_sizes, int n_in,
                              void* d_out, int out_size, void* d_ws, size_t ws_size,
                              hipStream_t stream) {
    const float* x     = (const float*)d_in[0];
    const int*   ei    = (const int*)d_in[1];
    const float* Wroot = (const float*)d_in[2];
    const float* Wrel  = (const float*)d_in[3];
    const float* brel  = (const float*)d_in[4];
    const float* gamma = (const float*)d_in[5];
    const float* beta  = (const float*)d_in[6];
    float* out = (float*)d_out;

    // workspace layout
    unsigned short* aggr_sl = (unsigned short*)d_ws;            // N*D
    unsigned short* x_sl    = aggr_sl + (size_t)N_NODES * D;    // N*D
    unsigned short* Wt      = x_sl + (size_t)N_NODES * D;       // 128*256
    float* gsum  = (float*)(Wt + 128 * 256);                    // 128 ─┐
    float* gss   = gsum + 128;                                  // 128  │ zeroed
    int* bcount  = (int*)(gss + 128);                           // 256 ─┘
    int* bucket_base = bcount + 256;                            // 256 (197 used)
    int* bcur    = bucket_base + 256;                           // 256
    unsigned* epk = (unsigned*)(bcur + 256);                    // N_EDGES (6.4 MB)

    hipMemsetAsync(gsum, 0, 512 * sizeof(int), stream);

    cvt_kernel<<<CVT_X_BLOCKS + 128, 256, 0, stream>>>(x, Wrel, Wroot, x_sl, Wt);
    bhist_kernel<<<BIN_BLOCKS, 256, 0, stream>>>(ei, bcount);
    bscan_kernel<<<1, 256, 0, stream>>>(bcount, bucket_base, bcur);
    binify_kernel<<<BIN_BLOCKS, 256, 0, stream>>>(ei, bcur, epk);
    gather_lds<<<NB * 8, 256, 0, stream>>>(x_sl, bucket_base, epk, aggr_sl);
    gemm_mfma<<<(N_NODES + 127) / 128, 256, 0, stream>>>(aggr_sl, x_sl, Wt, brel, out, gsum, gss);
    norm_kernel<<<12500, 256, 0, stream>>>(out, gsum, gss, gamma, beta);
}

// Round 7
// 295.949 us; speedup vs baseline: 4.6371x; 4.6371x over previous
//
#include <hip/hip_runtime.h>

#define N_NODES 100000
#define N_EDGES 1600000
#define D 128
#define NB 196              // buckets of 512 nodes: 196*512 = 100352 >= N_NODES
#define EPT 10              // edges per thread in binning
#define CHUNK 2560          // 256 threads * EPT
#define BIN_BLOCKS 625      // 625 * 2560 = 1,600,000 exactly
#define CVT_X_BLOCKS 6250   // 6250*256*8 = 12.8M elements

typedef __bf16 bf16x8 __attribute__((ext_vector_type(8)));
typedef float f32x4 __attribute__((ext_vector_type(4)));

__device__ __forceinline__ unsigned f2bf(float f) {
    unsigned u = __float_as_uint(f);
    return (u + 0x7fffu + ((u >> 16) & 1u)) >> 16;   // RNE
}
__device__ __forceinline__ float bf_lo(unsigned u) { return __uint_as_float(u << 16); }
__device__ __forceinline__ float bf_hi(unsigned u) { return __uint_as_float(u & 0xffff0000u); }

// ---------------- fused: x->bf16 (row-major) + Wt build + bucket histogram ----------------
__global__ __launch_bounds__(256) void prep_kernel(const float* __restrict__ x,
                                                   const float* __restrict__ Wrel,
                                                   const float* __restrict__ Wroot,
                                                   const int* __restrict__ ei,
                                                   unsigned short* __restrict__ x_bf,
                                                   unsigned short* __restrict__ Wt,
                                                   int* __restrict__ bcount) {
    __shared__ int h[256];
    int b = blockIdx.x;
    int t = threadIdx.x;
    if (b < CVT_X_BLOCKS) {
        size_t i = ((size_t)b * 256 + t) * 8;
        float4 v0 = *(const float4*)(x + i);
        float4 v1 = *(const float4*)(x + i + 4);
        uint4 p;
        p.x = f2bf(v0.x) | (f2bf(v0.y) << 16);
        p.y = f2bf(v0.z) | (f2bf(v0.w) << 16);
        p.z = f2bf(v1.x) | (f2bf(v1.y) << 16);
        p.w = f2bf(v1.z) | (f2bf(v1.w) << 16);
        *(uint4*)(x_bf + i) = p;
    } else if (b < CVT_X_BLOCKS + 128) {
        int c = b - CVT_X_BLOCKS;          // 0..127
        float v = (t < 128) ? Wrel[t * D + c] : Wroot[(t - 128) * D + c];
        Wt[c * 256 + t] = (unsigned short)f2bf(v);
    } else {
        int blk = b - (CVT_X_BLOCKS + 128);
        h[t] = 0;
        __syncthreads();
        int base = blk * CHUNK;
#pragma unroll
        for (int i = 0; i < EPT; ++i) {
            int dst = ei[N_EDGES + base + i * 256 + t];
            atomicAdd(&h[dst >> 9], 1);
        }
        __syncthreads();
        if (t < NB && h[t]) atomicAdd(&bcount[t], h[t]);
    }
}

// ---------------- bucket scan (1 block) ----------------
__global__ __launch_bounds__(256) void bscan_kernel(const int* __restrict__ bcount,
                                                    int* __restrict__ bucket_base,
                                                    int* __restrict__ bcur) {
    __shared__ int s[256];
    int t = threadIdx.x;
    int v = (t < NB) ? bcount[t] : 0;
    s[t] = v;
    __syncthreads();
    for (int off = 1; off < 256; off <<= 1) {
        int a = (t >= off) ? s[t - off] : 0;
        __syncthreads();
        s[t] += a;
        __syncthreads();
    }
    int excl = s[t] - v;
    if (t < NB) {
        bucket_base[t] = excl;
        bcur[t] = excl;
    }
    if (t == NB) bucket_base[NB] = N_EDGES;
}

// ---------------- binify: block-local multisplit, coalesced pair writes ----------------
__global__ __launch_bounds__(256) void binify_kernel(const int* __restrict__ ei,
                                                     int* __restrict__ bcur,
                                                     uint2* __restrict__ pairs) {
    __shared__ int lhist[256];
    __shared__ int lstart[256];
    __shared__ int lfill[256];
    __shared__ int gbase[256];
    __shared__ uint2 stage[CHUNK];

    int t = threadIdx.x;
    int base = blockIdx.x * CHUNK;
    lhist[t] = 0;
    lfill[t] = 0;
    __syncthreads();

    int src[EPT], dst[EPT];
#pragma unroll
    for (int i = 0; i < EPT; ++i) {
        int e = base + i * 256 + t;
        src[i] = ei[e];
        dst[i] = ei[N_EDGES + e];
        atomicAdd(&lhist[dst[i] >> 9], 1);
    }
    __syncthreads();

    int v = lhist[t];
    lstart[t] = v;
    __syncthreads();
    for (int off = 1; off < 256; off <<= 1) {
        int a = (t >= off) ? lstart[t - off] : 0;
        __syncthreads();
        lstart[t] += a;
        __syncthreads();
    }
    int excl = lstart[t] - v;
    if (t < NB && v > 0) gbase[t] = atomicAdd(&bcur[t], v);
    __syncthreads();
    lstart[t] = excl;
    __syncthreads();

#pragma unroll
    for (int i = 0; i < EPT; ++i) {
        int b = dst[i] >> 9;
        int lp = atomicAdd(&lfill[b], 1);
        stage[lstart[b] + lp] = make_uint2((unsigned)src[i], (unsigned)dst[i]);
    }
    __syncthreads();

    for (int i = t; i < CHUNK; i += 256) {
        uint2 p = stage[i];
        int b = (int)(p.y >> 9);
        pairs[gbase[b] + (i - lstart[b])] = p;
    }
}

// ---------------- place: per-bucket local count+scan -> rowstart, srcs ----------------
__global__ __launch_bounds__(256) void place_kernel(const uint2* __restrict__ pairs,
                                                    const int* __restrict__ bucket_base,
                                                    int* __restrict__ rowstart,
                                                    int* __restrict__ srcs) {
    __shared__ int bufA[512];
    __shared__ int bufB[512];
    int b = blockIdx.x;
    int t = threadIdx.x;
    int pbeg = bucket_base[b];
    int pend = bucket_base[b + 1];

    bufA[t] = 0;
    bufA[t + 256] = 0;
    __syncthreads();
    for (int i = pbeg + t; i < pend; i += 256)
        atomicAdd(&bufA[pairs[i].y & 511], 1);
    __syncthreads();

    for (int j = t; j < 512; j += 256) bufB[j] = j ? bufA[j - 1] : 0;
    __syncthreads();
    int* cur = bufB;
    int* nxt = bufA;
    for (int off = 1; off < 512; off <<= 1) {
        for (int j = t; j < 512; j += 256)
            nxt[j] = cur[j] + ((j >= off) ? cur[j - off] : 0);
        __syncthreads();
        int* tmp = cur; cur = nxt; nxt = tmp;
    }

    for (int j = t; j < 512; j += 256) {
        int gnode = (b << 9) + j;
        int val = pbeg + cur[j];
        if (gnode <= N_NODES) rowstart[gnode] = val;
        nxt[j] = val;
    }
    __syncthreads();

    for (int i = pbeg + t; i < pend; i += 256) {
        uint2 p = pairs[i];
        int pos = atomicAdd(&nxt[p.y & 511], 1);
        srcs[pos] = (int)p.x;
    }
}

// ---------------- gather: per-node, 64 lanes x float2, unroll 8 ----------------
__global__ __launch_bounds__(256) void gather_kernel(const unsigned short* __restrict__ x_bf,
                                                     const int* __restrict__ rowstart,
                                                     const int* __restrict__ srcs,
                                                     unsigned short* __restrict__ aggr_bf) {
    int t = threadIdx.x;
    int node = blockIdx.x * 4 + (t >> 6);
    int lane = t & 63;
    int begin = rowstart[node];
    int end = rowstart[node + 1];
    const unsigned short* xp = x_bf + lane * 2;
    float ax = 0.f, ay = 0.f;
    int e = begin;
    for (; e + 7 < end; e += 8) {
        int s0 = srcs[e],     s1 = srcs[e + 1], s2 = srcs[e + 2], s3 = srcs[e + 3];
        int s4 = srcs[e + 4], s5 = srcs[e + 5], s6 = srcs[e + 6], s7 = srcs[e + 7];
        unsigned u0 = *(const unsigned*)(xp + (size_t)s0 * D);
        unsigned u1 = *(const unsigned*)(xp + (size_t)s1 * D);
        unsigned u2 = *(const unsigned*)(xp + (size_t)s2 * D);
        unsigned u3 = *(const unsigned*)(xp + (size_t)s3 * D);
        unsigned u4 = *(const unsigned*)(xp + (size_t)s4 * D);
        unsigned u5 = *(const unsigned*)(xp + (size_t)s5 * D);
        unsigned u6 = *(const unsigned*)(xp + (size_t)s6 * D);
        unsigned u7 = *(const unsigned*)(xp + (size_t)s7 * D);
        ax += bf_lo(u0) + bf_lo(u1) + bf_lo(u2) + bf_lo(u3)
            + bf_lo(u4) + bf_lo(u5) + bf_lo(u6) + bf_lo(u7);
        ay += bf_hi(u0) + bf_hi(u1) + bf_hi(u2) + bf_hi(u3)
            + bf_hi(u4) + bf_hi(u5) + bf_hi(u6) + bf_hi(u7);
    }
    for (; e + 1 < end; e += 2) {
        int s0 = srcs[e], s1 = srcs[e + 1];
        unsigned u0 = *(const unsigned*)(xp + (size_t)s0 * D);
        unsigned u1 = *(const unsigned*)(xp + (size_t)s1 * D);
        ax += bf_lo(u0) + bf_lo(u1);
        ay += bf_hi(u0) + bf_hi(u1);
    }
    if (e < end) {
        unsigned u = *(const unsigned*)(xp + (size_t)srcs[e] * D);
        ax += bf_lo(u);
        ay += bf_hi(u);
    }
    *(unsigned*)(aggr_bf + (size_t)node * D + lane * 2) = f2bf(ax) | (f2bf(ay) << 16);
}

// ---------------- MFMA GEMM + fused BN stats; h stored bf16 ----------------
#define LDSTRIDE 40
__global__ __launch_bounds__(256) void gemm_mfma(const unsigned short* __restrict__ aggr_bf,
                                                 const unsigned short* __restrict__ x_bf,
                                                 const unsigned short* __restrict__ Wt,
                                                 const float* __restrict__ brel,
                                                 unsigned short* __restrict__ h_bf,
                                                 float* __restrict__ gsum,
                                                 float* __restrict__ gss) {
    __shared__ unsigned short As[128][LDSTRIDE];
    __shared__ unsigned short Bs[128][LDSTRIDE];
    __shared__ float sbias[128];
    __shared__ float SredS[4][128];
    __shared__ float SredQ[4][128];

    const int t = threadIdx.x;
    const int wave = t >> 6;
    const int lane = t & 63;
    const int quad = lane >> 4;
    const int l16 = lane & 15;
    const int blockRow = blockIdx.x * 128;

    if (t < 128) sbias[t] = brel[t];

    f32x4 acc[2][8];
#pragma unroll
    for (int i = 0; i < 2; ++i)
#pragma unroll
        for (int j = 0; j < 8; ++j) acc[i][j] = (f32x4){0.f, 0.f, 0.f, 0.f};

    for (int kc = 0; kc < 8; ++kc) {
        const unsigned short* Asrc = (kc < 4) ? aggr_bf : x_bf;
        const int k0 = (kc & 3) * 32;
#pragma unroll
        for (int s = t; s < 512; s += 256) {
            int row = s >> 2;
            int q = (s & 3) * 8;
            int grow = blockRow + row;
            uint4 v = make_uint4(0, 0, 0, 0);
            if (grow < N_NODES) v = *(const uint4*)(Asrc + (size_t)grow * D + k0 + q);
            *(uint4*)&As[row][q] = v;
        }
#pragma unroll
        for (int s = t; s < 512; s += 256) {
            int col = s >> 2;
            int q = (s & 3) * 8;
            uint4 v = *(const uint4*)(Wt + col * 256 + kc * 32 + q);
            *(uint4*)&Bs[col][q] = v;
        }
        __syncthreads();

        bf16x8 afrag0 = *(bf16x8*)&As[wave * 32 + l16][quad * 8];
        bf16x8 afrag1 = *(bf16x8*)&As[wave * 32 + 16 + l16][quad * 8];
#pragma unroll
        for (int ct = 0; ct < 8; ++ct) {
            bf16x8 bfrag = *(bf16x8*)&Bs[ct * 16 + l16][quad * 8];
            acc[0][ct] = __builtin_amdgcn_mfma_f32_16x16x32_bf16(afrag0, bfrag, acc[0][ct], 0, 0, 0);
            acc[1][ct] = __builtin_amdgcn_mfma_f32_16x16x32_bf16(afrag1, bfrag, acc[1][ct], 0, 0, 0);
        }
        __syncthreads();
    }

    float csum[8], css[8];
#pragma unroll
    for (int ct = 0; ct < 8; ++ct) { csum[ct] = 0.f; css[ct] = 0.f; }

#pragma unroll
    for (int rt = 0; rt < 2; ++rt) {
#pragma unroll
        for (int ct = 0; ct < 8; ++ct) {
            int col = ct * 16 + l16;
            float bv = sbias[col];
#pragma unroll
            for (int reg = 0; reg < 4; ++reg) {
                int row = blockRow + wave * 32 + rt * 16 + quad * 4 + reg;
                if (row < N_NODES) {
                    float v = acc[rt][ct][reg] + bv;
                    h_bf[(size_t)row * D + col] = (unsigned short)f2bf(v);
                    csum[ct] += v;
                    css[ct] += v * v;
                }
            }
        }
    }
#pragma unroll
    for (int ct = 0; ct < 8; ++ct) {
        float s = csum[ct], q = css[ct];
        s += __shfl_xor(s, 16);
        s += __shfl_xor(s, 32);
        q += __shfl_xor(q, 16);
        q += __shfl_xor(q, 32);
        if (quad == 0) {
            SredS[wave][ct * 16 + l16] = s;
            SredQ[wave][ct * 16 + l16] = q;
        }
    }
    __syncthreads();
    if (t < 128) {
        float s = SredS[0][t] + SredS[1][t] + SredS[2][t] + SredS[3][t];
        float q = SredQ[0][t] + SredQ[1][t] + SredQ[2][t] + SredQ[3][t];
        unsafeAtomicAdd(&gsum[t], s);
        unsafeAtomicAdd(&gss[t], q);
    }
}

// ---------------- normalize + relu: read h_bf, write f32 out ----------------
__global__ __launch_bounds__(256) void norm_kernel(const unsigned short* __restrict__ h_bf,
                                                   float* __restrict__ out,
                                                   const float* __restrict__ gsum,
                                                   const float* __restrict__ gss,
                                                   const float* __restrict__ gamma,
                                                   const float* __restrict__ beta) {
    __shared__ float sscale[128];
    __shared__ float sshift[128];
    int t = threadIdx.x;
    if (t < 128) {
        const float inv_n = 1.0f / (float)N_NODES;
        float mean = gsum[t] * inv_n;
        float var = gss[t] * inv_n - mean * mean;
        float rs = rsqrtf(var + 1e-5f);
        float sc = gamma[t] * rs;
        sscale[t] = sc;
        sshift[t] = beta[t] - mean * sc;
    }
    __syncthreads();
    size_t e = ((size_t)blockIdx.x * 256 + t) * 4;
    if (e >= (size_t)N_NODES * D) return;
    int c = (int)(e & 127);
    uint2 u = *(const uint2*)(h_bf + e);
    float4 v;
    v.x = fmaxf(bf_lo(u.x) * sscale[c + 0] + sshift[c + 0], 0.f);
    v.y = fmaxf(bf_hi(u.x) * sscale[c + 1] + sshift[c + 1], 0.f);
    v.z = fmaxf(bf_lo(u.y) * sscale[c + 2] + sshift[c + 2], 0.f);
    v.w = fmaxf(bf_hi(u.y) * sscale[c + 3] + sshift[c + 3], 0.f);
    *(float4*)(out + e) = v;
}

extern "C" void kernel_launch(void* const* d_in, const int* in_sizes, int n_in,
                              void* d_out, int out_size, void* d_ws, size_t ws_size,
                              hipStream_t stream) {
    const float* x     = (const float*)d_in[0];
    const int*   ei    = (const int*)d_in[1];
    const float* Wroot = (const float*)d_in[2];
    const float* Wrel  = (const float*)d_in[3];
    const float* brel  = (const float*)d_in[4];
    const float* gamma = (const float*)d_in[5];
    const float* beta  = (const float*)d_in[6];
    float* out = (float*)d_out;

    // workspace layout; h_bf aliases (pairs,srcs) which are dead by gemm time
    unsigned short* aggr_bf = (unsigned short*)d_ws;            // N*D (25.6 MB)
    unsigned short* x_bf    = aggr_bf + (size_t)N_NODES * D;    // N*D (25.6 MB)
    unsigned short* Wt      = x_bf + (size_t)N_NODES * D;       // 128*256
    float* gsum  = (float*)(Wt + 128 * 256);                    // 128 ─┐
    float* gss   = gsum + 128;                                  // 128  │ zeroed
    int* bcount  = (int*)(gss + 128);                           // 256 ─┘
    int* bucket_base = bcount + 256;                            // 256 (197 used)
    int* bcur    = bucket_base + 256;                           // 256
    int* rowstart = bcur + 256;                                 // 100352
    uint2* pairs = (uint2*)(rowstart + 100352);                 // N_EDGES (12.8 MB)
    int* srcs    = (int*)(pairs + N_EDGES);                     // N_EDGES (6.4 MB)
    unsigned short* h_bf = (unsigned short*)pairs;              // N*D (25.6 MB) alias

    hipMemsetAsync(gsum, 0, 512 * sizeof(int), stream);

    prep_kernel<<<CVT_X_BLOCKS + 128 + BIN_BLOCKS, 256, 0, stream>>>(
        x, Wrel, Wroot, ei, x_bf, Wt, bcount);
    bscan_kernel<<<1, 256, 0, stream>>>(bcount, bucket_base, bcur);
    binify_kernel<<<BIN_BLOCKS, 256, 0, stream>>>(ei, bcur, pairs);
    place_kernel<<<NB, 256, 0, stream>>>(pairs, bucket_base, rowstart, srcs);
    gather_kernel<<<N_NODES / 4, 256, 0, stream>>>(x_bf, rowstart, srcs, aggr_bf);
    gemm_mfma<<<(N_NODES + 127) / 128, 256, 0, stream>>>(aggr_bf, x_bf, Wt, brel, h_bf, gsum, gss);
    norm_kernel<<<12500, 256, 0, stream>>>(h_bf, out, gsum, gss, gamma, beta);
}

// Round 8
// 292.345 us; speedup vs baseline: 4.6943x; 1.0123x over previous
//
#include <hip/hip_runtime.h>

#define N_NODES 100000
#define N_EDGES 1600000
#define D 128
#define NB 196              // buckets of 512 nodes: 196*512 = 100352 >= N_NODES
#define EPT 10              // edges per thread in binning
#define CHUNK 2560          // 256 threads * EPT
#define BIN_BLOCKS 625      // 625 * 2560 = 1,600,000 exactly
#define CVT_X_BLOCKS 6250   // 6250*256*8 = 12.8M elements

typedef __bf16 bf16x8 __attribute__((ext_vector_type(8)));
typedef float f32x4 __attribute__((ext_vector_type(4)));

__device__ __forceinline__ unsigned f2bf(float f) {
    unsigned u = __float_as_uint(f);
    return (u + 0x7fffu + ((u >> 16) & 1u)) >> 16;   // RNE
}
__device__ __forceinline__ float bf_lo(unsigned u) { return __uint_as_float(u << 16); }
__device__ __forceinline__ float bf_hi(unsigned u) { return __uint_as_float(u & 0xffff0000u); }

// ---------------- fused: x->bf16 (row-major) + Wt build + bucket histogram ----------------
__global__ __launch_bounds__(256) void prep_kernel(const float* __restrict__ x,
                                                   const float* __restrict__ Wrel,
                                                   const float* __restrict__ Wroot,
                                                   const int* __restrict__ ei,
                                                   unsigned short* __restrict__ x_bf,
                                                   unsigned short* __restrict__ Wt,
                                                   int* __restrict__ bcount) {
    __shared__ int h[256];
    int b = blockIdx.x;
    int t = threadIdx.x;
    if (b < CVT_X_BLOCKS) {
        size_t i = ((size_t)b * 256 + t) * 8;
        float4 v0 = *(const float4*)(x + i);
        float4 v1 = *(const float4*)(x + i + 4);
        uint4 p;
        p.x = f2bf(v0.x) | (f2bf(v0.y) << 16);
        p.y = f2bf(v0.z) | (f2bf(v0.w) << 16);
        p.z = f2bf(v1.x) | (f2bf(v1.y) << 16);
        p.w = f2bf(v1.z) | (f2bf(v1.w) << 16);
        *(uint4*)(x_bf + i) = p;
    } else if (b < CVT_X_BLOCKS + 128) {
        int c = b - CVT_X_BLOCKS;          // 0..127
        float v = (t < 128) ? Wrel[t * D + c] : Wroot[(t - 128) * D + c];
        Wt[c * 256 + t] = (unsigned short)f2bf(v);
    } else {
        int blk = b - (CVT_X_BLOCKS + 128);
        h[t] = 0;
        __syncthreads();
        int base = blk * CHUNK;
#pragma unroll
        for (int i = 0; i < EPT; ++i) {
            int dst = ei[N_EDGES + base + i * 256 + t];
            atomicAdd(&h[dst >> 9], 1);
        }
        __syncthreads();
        if (t < NB && h[t]) atomicAdd(&bcount[t], h[t]);
    }
}

// ---------------- bucket scan (1 block) ----------------
__global__ __launch_bounds__(256) void bscan_kernel(const int* __restrict__ bcount,
                                                    int* __restrict__ bucket_base,
                                                    int* __restrict__ bcur) {
    __shared__ int s[256];
    int t = threadIdx.x;
    int v = (t < NB) ? bcount[t] : 0;
    s[t] = v;
    __syncthreads();
    for (int off = 1; off < 256; off <<= 1) {
        int a = (t >= off) ? s[t - off] : 0;
        __syncthreads();
        s[t] += a;
        __syncthreads();
    }
    int excl = s[t] - v;
    if (t < NB) {
        bucket_base[t] = excl;
        bcur[t] = excl;
    }
    if (t == NB) bucket_base[NB] = N_EDGES;
}

// ---------------- binify: block-local multisplit -> packed 4B edge codes ----------------
// code: src in bits 0..16, local dst (dst&511) in bits 17..25
__global__ __launch_bounds__(256) void binify_kernel(const int* __restrict__ ei,
                                                     int* __restrict__ bcur,
                                                     unsigned* __restrict__ epk) {
    __shared__ int lhist[256];
    __shared__ int lstart[256];
    __shared__ int lfill[256];
    __shared__ int gbase[256];
    __shared__ uint2 stage[CHUNK];

    int t = threadIdx.x;
    int base = blockIdx.x * CHUNK;
    lhist[t] = 0;
    lfill[t] = 0;
    __syncthreads();

    int src[EPT], dst[EPT];
#pragma unroll
    for (int i = 0; i < EPT; ++i) {
        int e = base + i * 256 + t;
        src[i] = ei[e];
        dst[i] = ei[N_EDGES + e];
        atomicAdd(&lhist[dst[i] >> 9], 1);
    }
    __syncthreads();

    int v = lhist[t];
    lstart[t] = v;
    __syncthreads();
    for (int off = 1; off < 256; off <<= 1) {
        int a = (t >= off) ? lstart[t - off] : 0;
        __syncthreads();
        lstart[t] += a;
        __syncthreads();
    }
    int excl = lstart[t] - v;
    if (t < NB && v > 0) gbase[t] = atomicAdd(&bcur[t], v);
    __syncthreads();
    lstart[t] = excl;
    __syncthreads();

#pragma unroll
    for (int i = 0; i < EPT; ++i) {
        int b = dst[i] >> 9;
        int lp = atomicAdd(&lfill[b], 1);
        stage[lstart[b] + lp] = make_uint2((unsigned)src[i], (unsigned)dst[i]);
    }
    __syncthreads();

    for (int i = t; i < CHUNK; i += 256) {
        uint2 p = stage[i];
        int b = (int)(p.y >> 9);
        unsigned code = p.x | ((p.y & 511u) << 17);
        epk[gbase[b] + (i - lstart[b])] = code;
    }
}

// ---------------- place: per-bucket local count+scan -> rowstart, srcs ----------------
__global__ __launch_bounds__(256) void place_kernel(const unsigned* __restrict__ epk,
                                                    const int* __restrict__ bucket_base,
                                                    int* __restrict__ rowstart,
                                                    int* __restrict__ srcs) {
    __shared__ int bufA[512];
    __shared__ int bufB[512];
    int b = blockIdx.x;
    int t = threadIdx.x;
    int pbeg = bucket_base[b];
    int pend = bucket_base[b + 1];

    bufA[t] = 0;
    bufA[t + 256] = 0;
    __syncthreads();
    for (int i = pbeg + t; i < pend; i += 256)
        atomicAdd(&bufA[epk[i] >> 17], 1);
    __syncthreads();

    for (int j = t; j < 512; j += 256) bufB[j] = j ? bufA[j - 1] : 0;
    __syncthreads();
    int* cur = bufB;
    int* nxt = bufA;
    for (int off = 1; off < 512; off <<= 1) {
        for (int j = t; j < 512; j += 256)
            nxt[j] = cur[j] + ((j >= off) ? cur[j - off] : 0);
        __syncthreads();
        int* tmp = cur; cur = nxt; nxt = tmp;
    }

    for (int j = t; j < 512; j += 256) {
        int gnode = (b << 9) + j;
        int val = pbeg + cur[j];
        if (gnode <= N_NODES) rowstart[gnode] = val;
        nxt[j] = val;
    }
    __syncthreads();

    for (int i = pbeg + t; i < pend; i += 256) {
        unsigned code = epk[i];
        int pos = atomicAdd(&nxt[code >> 17], 1);
        srcs[pos] = (int)(code & 0x1FFFFu);
    }
}

// ---------------- gather: half-wave per node (32 lanes x 4ch), unroll 8 ----------------
// one global_load covers TWO rows (512 B/inst); 4 KB in flight per wave
__global__ __launch_bounds__(256) void gather_kernel(const unsigned short* __restrict__ x_bf,
                                                     const int* __restrict__ rowstart,
                                                     const int* __restrict__ srcs,
                                                     unsigned short* __restrict__ aggr_bf) {
    int t = threadIdx.x;
    int node = blockIdx.x * 8 + (t >> 5);
    int lane = t & 31;
    int begin = rowstart[node];
    int end = rowstart[node + 1];
    const unsigned short* xp = x_bf + lane * 4;
    float a0 = 0.f, a1 = 0.f, a2 = 0.f, a3 = 0.f;
    int e = begin;
    for (; e + 7 < end; e += 8) {
        int s0 = srcs[e],     s1 = srcs[e + 1], s2 = srcs[e + 2], s3 = srcs[e + 3];
        int s4 = srcs[e + 4], s5 = srcs[e + 5], s6 = srcs[e + 6], s7 = srcs[e + 7];
        uint2 u0 = *(const uint2*)(xp + (size_t)s0 * D);
        uint2 u1 = *(const uint2*)(xp + (size_t)s1 * D);
        uint2 u2 = *(const uint2*)(xp + (size_t)s2 * D);
        uint2 u3 = *(const uint2*)(xp + (size_t)s3 * D);
        uint2 u4 = *(const uint2*)(xp + (size_t)s4 * D);
        uint2 u5 = *(const uint2*)(xp + (size_t)s5 * D);
        uint2 u6 = *(const uint2*)(xp + (size_t)s6 * D);
        uint2 u7 = *(const uint2*)(xp + (size_t)s7 * D);
        a0 += bf_lo(u0.x) + bf_lo(u1.x) + bf_lo(u2.x) + bf_lo(u3.x)
            + bf_lo(u4.x) + bf_lo(u5.x) + bf_lo(u6.x) + bf_lo(u7.x);
        a1 += bf_hi(u0.x) + bf_hi(u1.x) + bf_hi(u2.x) + bf_hi(u3.x)
            + bf_hi(u4.x) + bf_hi(u5.x) + bf_hi(u6.x) + bf_hi(u7.x);
        a2 += bf_lo(u0.y) + bf_lo(u1.y) + bf_lo(u2.y) + bf_lo(u3.y)
            + bf_lo(u4.y) + bf_lo(u5.y) + bf_lo(u6.y) + bf_lo(u7.y);
        a3 += bf_hi(u0.y) + bf_hi(u1.y) + bf_hi(u2.y) + bf_hi(u3.y)
            + bf_hi(u4.y) + bf_hi(u5.y) + bf_hi(u6.y) + bf_hi(u7.y);
    }
    for (; e + 1 < end; e += 2) {
        int s0 = srcs[e], s1 = srcs[e + 1];
        uint2 u0 = *(const uint2*)(xp + (size_t)s0 * D);
        uint2 u1 = *(const uint2*)(xp + (size_t)s1 * D);
        a0 += bf_lo(u0.x) + bf_lo(u1.x);
        a1 += bf_hi(u0.x) + bf_hi(u1.x);
        a2 += bf_lo(u0.y) + bf_lo(u1.y);
        a3 += bf_hi(u0.y) + bf_hi(u1.y);
    }
    if (e < end) {
        uint2 u = *(const uint2*)(xp + (size_t)srcs[e] * D);
        a0 += bf_lo(u.x);
        a1 += bf_hi(u.x);
        a2 += bf_lo(u.y);
        a3 += bf_hi(u.y);
    }
    uint2 w;
    w.x = f2bf(a0) | (f2bf(a1) << 16);
    w.y = f2bf(a2) | (f2bf(a3) << 16);
    *(uint2*)(aggr_bf + (size_t)node * D + lane * 4) = w;
}

// ---------------- MFMA GEMM + fused BN stats; h stored bf16 ----------------
#define LDSTRIDE 40
__global__ __launch_bounds__(256) void gemm_mfma(const unsigned short* __restrict__ aggr_bf,
                                                 const unsigned short* __restrict__ x_bf,
                                                 const unsigned short* __restrict__ Wt,
                                                 const float* __restrict__ brel,
                                                 unsigned short* __restrict__ h_bf,
                                                 float* __restrict__ gsum,
                                                 float* __restrict__ gss) {
    __shared__ unsigned short As[128][LDSTRIDE];
    __shared__ unsigned short Bs[128][LDSTRIDE];
    __shared__ float sbias[128];
    __shared__ float SredS[4][128];
    __shared__ float SredQ[4][128];

    const int t = threadIdx.x;
    const int wave = t >> 6;
    const int lane = t & 63;
    const int quad = lane >> 4;
    const int l16 = lane & 15;
    const int blockRow = blockIdx.x * 128;

    if (t < 128) sbias[t] = brel[t];

    f32x4 acc[2][8];
#pragma unroll
    for (int i = 0; i < 2; ++i)
#pragma unroll
        for (int j = 0; j < 8; ++j) acc[i][j] = (f32x4){0.f, 0.f, 0.f, 0.f};

    for (int kc = 0; kc < 8; ++kc) {
        const unsigned short* Asrc = (kc < 4) ? aggr_bf : x_bf;
        const int k0 = (kc & 3) * 32;
#pragma unroll
        for (int s = t; s < 512; s += 256) {
            int row = s >> 2;
            int q = (s & 3) * 8;
            int grow = blockRow + row;
            uint4 v = make_uint4(0, 0, 0, 0);
            if (grow < N_NODES) v = *(const uint4*)(Asrc + (size_t)grow * D + k0 + q);
            *(uint4*)&As[row][q] = v;
        }
#pragma unroll
        for (int s = t; s < 512; s += 256) {
            int col = s >> 2;
            int q = (s & 3) * 8;
            uint4 v = *(const uint4*)(Wt + col * 256 + kc * 32 + q);
            *(uint4*)&Bs[col][q] = v;
        }
        __syncthreads();

        bf16x8 afrag0 = *(bf16x8*)&As[wave * 32 + l16][quad * 8];
        bf16x8 afrag1 = *(bf16x8*)&As[wave * 32 + 16 + l16][quad * 8];
#pragma unroll
        for (int ct = 0; ct < 8; ++ct) {
            bf16x8 bfrag = *(bf16x8*)&Bs[ct * 16 + l16][quad * 8];
            acc[0][ct] = __builtin_amdgcn_mfma_f32_16x16x32_bf16(afrag0, bfrag, acc[0][ct], 0, 0, 0);
            acc[1][ct] = __builtin_amdgcn_mfma_f32_16x16x32_bf16(afrag1, bfrag, acc[1][ct], 0, 0, 0);
        }
        __syncthreads();
    }

    float csum[8], css[8];
#pragma unroll
    for (int ct = 0; ct < 8; ++ct) { csum[ct] = 0.f; css[ct] = 0.f; }

#pragma unroll
    for (int rt = 0; rt < 2; ++rt) {
#pragma unroll
        for (int ct = 0; ct < 8; ++ct) {
            int col = ct * 16 + l16;
            float bv = sbias[col];
#pragma unroll
            for (int reg = 0; reg < 4; ++reg) {
                int row = blockRow + wave * 32 + rt * 16 + quad * 4 + reg;
                if (row < N_NODES) {
                    float v = acc[rt][ct][reg] + bv;
                    h_bf[(size_t)row * D + col] = (unsigned short)f2bf(v);
                    csum[ct] += v;
                    css[ct] += v * v;
                }
            }
        }
    }
#pragma unroll
    for (int ct = 0; ct < 8; ++ct) {
        float s = csum[ct], q = css[ct];
        s += __shfl_xor(s, 16);
        s += __shfl_xor(s, 32);
        q += __shfl_xor(q, 16);
        q += __shfl_xor(q, 32);
        if (quad == 0) {
            SredS[wave][ct * 16 + l16] = s;
            SredQ[wave][ct * 16 + l16] = q;
        }
    }
    __syncthreads();
    if (t < 128) {
        float s = SredS[0][t] + SredS[1][t] + SredS[2][t] + SredS[3][t];
        float q = SredQ[0][t] + SredQ[1][t] + SredQ[2][t] + SredQ[3][t];
        unsafeAtomicAdd(&gsum[t], s);
        unsafeAtomicAdd(&gss[t], q);
    }
}

// ---------------- normalize + relu: read h_bf, write f32 out ----------------
__global__ __launch_bounds__(256) void norm_kernel(const unsigned short* __restrict__ h_bf,
                                                   float* __restrict__ out,
                                                   const float* __restrict__ gsum,
                                                   const float* __restrict__ gss,
                                                   const float* __restrict__ gamma,
                                                   const float* __restrict__ beta) {
    __shared__ float sscale[128];
    __shared__ float sshift[128];
    int t = threadIdx.x;
    if (t < 128) {
        const float inv_n = 1.0f / (float)N_NODES;
        float mean = gsum[t] * inv_n;
        float var = gss[t] * inv_n - mean * mean;
        float rs = rsqrtf(var + 1e-5f);
        float sc = gamma[t] * rs;
        sscale[t] = sc;
        sshift[t] = beta[t] - mean * sc;
    }
    __syncthreads();
    size_t e = ((size_t)blockIdx.x * 256 + t) * 4;
    if (e >= (size_t)N_NODES * D) return;
    int c = (int)(e & 127);
    uint2 u = *(const uint2*)(h_bf + e);
    float4 v;
    v.x = fmaxf(bf_lo(u.x) * sscale[c + 0] + sshift[c + 0], 0.f);
    v.y = fmaxf(bf_hi(u.x) * sscale[c + 1] + sshift[c + 1], 0.f);
    v.z = fmaxf(bf_lo(u.y) * sscale[c + 2] + sshift[c + 2], 0.f);
    v.w = fmaxf(bf_hi(u.y) * sscale[c + 3] + sshift[c + 3], 0.f);
    *(float4*)(out + e) = v;
}

extern "C" void kernel_launch(void* const* d_in, const int* in_sizes, int n_in,
                              void* d_out, int out_size, void* d_ws, size_t ws_size,
                              hipStream_t stream) {
    const float* x     = (const float*)d_in[0];
    const int*   ei    = (const int*)d_in[1];
    const float* Wroot = (const float*)d_in[2];
    const float* Wrel  = (const float*)d_in[3];
    const float* brel  = (const float*)d_in[4];
    const float* gamma = (const float*)d_in[5];
    const float* beta  = (const float*)d_in[6];
    float* out = (float*)d_out;

    // workspace layout; h_bf aliases (epk,srcs) which are dead by gemm time
    unsigned short* aggr_bf = (unsigned short*)d_ws;            // N*D (25.6 MB)
    unsigned short* x_bf    = aggr_bf + (size_t)N_NODES * D;    // N*D (25.6 MB)
    unsigned short* Wt      = x_bf + (size_t)N_NODES * D;       // 128*256
    float* gsum  = (float*)(Wt + 128 * 256);                    // 128 ─┐
    float* gss   = gsum + 128;                                  // 128  │ zeroed
    int* bcount  = (int*)(gss + 128);                           // 256 ─┘
    int* bucket_base = bcount + 256;                            // 256 (197 used)
    int* bcur    = bucket_base + 256;                           // 256
    int* rowstart = bcur + 256;                                 // 100352
    unsigned* epk = (unsigned*)(rowstart + 100352);             // N_EDGES (6.4 MB)
    int* srcs    = (int*)(epk + N_EDGES);                       // N_EDGES (6.4 MB)
    unsigned short* h_bf = (unsigned short*)epk;                // N*D (25.6 MB) alias

    hipMemsetAsync(gsum, 0, 512 * sizeof(int), stream);

    prep_kernel<<<CVT_X_BLOCKS + 128 + BIN_BLOCKS, 256, 0, stream>>>(
        x, Wrel, Wroot, ei, x_bf, Wt, bcount);
    bscan_kernel<<<1, 256, 0, stream>>>(bcount, bucket_base, bcur);
    binify_kernel<<<BIN_BLOCKS, 256, 0, stream>>>(ei, bcur, epk);
    place_kernel<<<NB, 256, 0, stream>>>(epk, bucket_base, rowstart, srcs);
    gather_kernel<<<N_NODES / 8, 256, 0, stream>>>(x_bf, rowstart, srcs, aggr_bf);
    gemm_mfma<<<(N_NODES + 127) / 128, 256, 0, stream>>>(aggr_bf, x_bf, Wt, brel, h_bf, gsum, gss);
    norm_kernel<<<12500, 256, 0, stream>>>(h_bf, out, gsum, gss, gamma, beta);
}